// Round 4
// baseline (420.210 us; speedup 1.0000x reference)
//
#include <hip/hip_runtime.h>

// Problem constants (match reference)
#define D    128      // embedding dim
#define VSZ  200000   // vocab (emb has VSZ+1 rows, last row = 0)
#define NB   4096     // batch B
#define MM   50       // neighbors
#define DM   256      // 2*D
#define HSZ  512      // H
#define G4   2048     // 4*H

typedef __attribute__((ext_vector_type(8))) short short8;   // 8 bf16 = 4 VGPRs
typedef __attribute__((ext_vector_type(4))) float floatx4;  // MFMA acc

__device__ __forceinline__ float sigf(float x) { return 1.0f / (1.0f + __expf(-x)); }
__device__ __forceinline__ float tanhfast(float x) { return 1.0f - 2.0f / (__expf(2.0f * x) + 1.0f); }
__device__ __forceinline__ unsigned short f2bf(float x) {
    unsigned int u = __float_as_uint(x);
    u += 0x7FFFu + ((u >> 16) & 1u);   // round-to-nearest-even
    return (unsigned short)(u >> 16);
}
__device__ __forceinline__ float bf2f(unsigned short s) {
    return __uint_as_float(((unsigned int)s) << 16);
}

// async 16B global->LDS DMA (gfx950).  lds dest must be wave-uniform;
// HW writes dest + lane*16.  size must be a literal (4/12/16).
__device__ __forceinline__ void async_copy16(void* lds, const void* gsrc) {
    __builtin_amdgcn_global_load_lds(
        (const __attribute__((address_space(1))) unsigned int*)gsrc,
        (__attribute__((address_space(3))) unsigned int*)lds, 16, 0, 0);
}

// ---------------------------------------------------------------------------
// Kernel 0 (merged): pack Wih (2048x256) and Whh[:, :256] into fragment-linear
// bf16 (chunk idx = (tile*8+ks)*64+lane), gb = bih+bhh, AND repack gcn_W
// (128x256 fp32) into bf16 Wb[n][k] (old k_wconv -- merged to save a launch).
// ---------------------------------------------------------------------------
__global__ __launch_bounds__(256) void k_pack(
    const float* __restrict__ Wih, const float* __restrict__ Whh,
    const float* __restrict__ bih, const float* __restrict__ bhh,
    const float* __restrict__ gcn_W,
    unsigned short* __restrict__ Wihp, unsigned short* __restrict__ Whhp,
    float* __restrict__ gb, unsigned short* __restrict__ Wb)
{
    int idx = blockIdx.x * 256 + threadIdx.x;
    if (idx < 131072) {
        int ci = idx & 65535;
        int lane = ci & 63, rest = ci >> 6;
        int ks = rest & 7, tile = rest >> 3;
        int n = tile * 16 + (lane & 15), k = ks * 32 + (lane >> 4) * 8;
        const float* src = (idx < 65536) ? (Wih + (size_t)n * 256 + k)
                                         : (Whh + (size_t)n * 512 + k);
        unsigned short* dst = (idx < 65536) ? Wihp : Whhp;
        short8 o;
        #pragma unroll
        for (int j = 0; j < 8; ++j) o[j] = (short)f2bf(src[j]);
        *(short8*)(dst + (size_t)ci * 8) = o;
    } else if (idx < 131072 + 2048) {
        int i = idx - 131072;
        gb[i] = bih[i] + bhh[i];
    } else if (idx < 131072 + 2048 + 32768) {
        int i = idx - (131072 + 2048);
        int n = i >> 7, k = i & 127;
        float v = (n < 128) ? gcn_W[n * 256 + k] : gcn_W[(n - 128) * 256 + 128 + k];
        Wb[i] = f2bf(v);
    }
}

// ---------------------------------------------------------------------------
// Kernel 1: P = emb @ Wcat^T via bf16 MFMA.  Round-9: 32-row blocks +
// convert-ONCE.  R3 (DMA staging) confirmed the MLP theory (96->80us,
// 1.6->2.17 TB/s) but left 4x-redundant per-wave f2bf conversion (~400 VALU
// inst/lane) and only 4 blocks/CU.  Now: DMA 16KB fp32 (source pre-swizzled
// byte^=(row&7)<<5) -> one convert pass (16 cvt/lane) into a padded bf16
// tile [32][136] -> MFMA reads single ds_read_b128 fragments (2-way bank =
// free).  LDS 24.5KB, 5 blocks/CU via __launch_bounds__(256,5) (VGPR cap
// 102; acc is 32 regs).  4 barriers, none after global stores.
// Tripwires: WRITE>108MB => spill; dur>=70us => write-path wall, pivot.
// ---------------------------------------------------------------------------
__global__ __launch_bounds__(256, 5) void k_proj_mfma(
    const float* __restrict__ emb, const unsigned short* __restrict__ Wb,
    const float* __restrict__ gcn_lb, const float* __restrict__ gcn_b,
    unsigned short* __restrict__ P1, unsigned short* __restrict__ P2, int nrows)
{
    __shared__ __align__(16) unsigned char SB[25088];
    unsigned short* Ab = (unsigned short*)(SB + 16384);  // bf16 [32][136]
    unsigned short* C  = (unsigned short*)SB;            // reuse: [32][264]

    int t = threadIdx.x;
    int v0 = blockIdx.x * 32;
    int lane = t & 63, w = t >> 6;
    int nl = lane & 15, quad = lane >> 4;
    int n0 = w * 64;

    // ---- stage A: 32 rows x 512 B via async DMA, source pre-swizzled ----
    #pragma unroll
    for (int it = 0; it < 4; ++it) {
        int chunk = w * 4 + it;                   // 16 chunks of 1KB
        int o = chunk * 1024 + lane * 16;         // linear LDS byte
        int row = o >> 9;
        int b = o & 511;
        int bs = b ^ ((row & 7) << 5);            // inverse swizzle on source
        int v = v0 + row;
        v = (v < nrows) ? v : (nrows - 1);        // clamp tail (stores guarded)
        async_copy16(SB + chunk * 1024,
                     (const char*)emb + (size_t)v * 512 + bs);
    }
    __syncthreads();

    // ---- convert ONCE: fp32 (swizzled) -> bf16 [32][136] ----
    #pragma unroll
    for (int it = 0; it < 2; ++it) {
        int c = t + 256 * it;                     // 512 chunks of 8 bf16
        int row = c >> 4, c8 = c & 15;
        int cb = (c8 * 32) ^ ((row & 7) << 5);    // swizzled 32B block
        const float* src = (const float*)(SB + row * 512 + cb);
        float4 lo = *(const float4*)src;
        float4 hi = *(const float4*)(src + 4);
        short8 a;
        a[0] = (short)f2bf(lo.x); a[1] = (short)f2bf(lo.y);
        a[2] = (short)f2bf(lo.z); a[3] = (short)f2bf(lo.w);
        a[4] = (short)f2bf(hi.x); a[5] = (short)f2bf(hi.y);
        a[6] = (short)f2bf(hi.z); a[7] = (short)f2bf(hi.w);
        *(short8*)(Ab + row * 136 + c8 * 8) = a;
    }
    __syncthreads();

    floatx4 acc[2][4];
    #pragma unroll
    for (int mt = 0; mt < 2; ++mt)
        #pragma unroll
        for (int nt = 0; nt < 4; ++nt)
            acc[mt][nt] = (floatx4){0.f, 0.f, 0.f, 0.f};

    #pragma unroll
    for (int ks = 0; ks < 4; ++ks) {
        short8 bfr[4], af[2];
        #pragma unroll
        for (int nt = 0; nt < 4; ++nt)
            bfr[nt] = *(const short8*)(Wb + (size_t)(n0 + nt * 16 + nl) * 128 + ks * 32 + quad * 8);
        #pragma unroll
        for (int mt = 0; mt < 2; ++mt)
            af[mt] = *(const short8*)(Ab + (mt * 16 + nl) * 136 + ks * 32 + quad * 8);
        #pragma unroll
        for (int mt = 0; mt < 2; ++mt)
            #pragma unroll
            for (int nt = 0; nt < 4; ++nt)
                acc[mt][nt] = __builtin_amdgcn_mfma_f32_16x16x32_bf16(
                    af[mt], bfr[nt], acc[mt][nt], 0, 0, 0);
    }

    __syncthreads();   // all waves done with Ab; C overlaps staged regions
    #pragma unroll
    for (int nt = 0; nt < 4; ++nt) {
        int col = n0 + nt * 16 + nl;
        float bias = (col < 128) ? (gcn_lb[col] + gcn_b[col]) : 0.f;
        #pragma unroll
        for (int mt = 0; mt < 2; ++mt)
            #pragma unroll
            for (int reg = 0; reg < 4; ++reg)
                C[(mt * 16 + quad * 4 + reg) * 264 + col] =
                    f2bf(acc[mt][nt][reg] + bias);
    }
    __syncthreads();
    #pragma unroll
    for (int it = 0; it < 4; ++it) {
        int c = t + 256 * it;                     // 1024 16B chunks
        int row = c >> 5, c8 = c & 31;
        int v = v0 + row;
        if (v < nrows) {
            int4 val = *(const int4*)(C + row * 264 + c8 * 8);
            unsigned short* dst = (c8 < 16) ? (P1 + (size_t)v * D + c8 * 8)
                                            : (P2 + (size_t)v * D + (c8 - 16) * 8);
            *(int4*)dst = val;
        }
    }
}

// ---------------------------------------------------------------------------
// Kernel 2: neighbor aggregation, both conn tables concurrently.
// One block per (item, side).  16B gathers (8 bf16 per load).
// ---------------------------------------------------------------------------
__global__ __launch_bounds__(256) void k_nbr(
    const int* __restrict__ query, const int* __restrict__ support,
    const int* __restrict__ q_l1, const int* __restrict__ q_l2,
    const int* __restrict__ q_r1, const int* __restrict__ q_r2,
    const int* __restrict__ s_l1, const int* __restrict__ s_l2,
    const int* __restrict__ s_r1, const int* __restrict__ s_r2,
    const unsigned short* __restrict__ P1, const unsigned short* __restrict__ P2,
    const float* __restrict__ emb,
    const float* __restrict__ attn_W, const float* __restrict__ attn_b,
    const float* __restrict__ gate_W, const float* __restrict__ gate_lb,
    const float* __restrict__ gate_b,
    float* __restrict__ qv, unsigned short* __restrict__ qvbf,
    float* __restrict__ sv)
{
    __shared__ unsigned short proj[2 * MM * 136];   // bf16, 27.2 KB
    __shared__ int rel[2 * MM], ent[2 * MM];
    __shared__ float scw[2 * 64];
    __shared__ float scp[2][2][64];
    __shared__ float aw[D], gw[D];
    __shared__ float redg[4];
    __shared__ float gateS[2];
    __shared__ float oth[D];

    int bid = blockIdx.x;
    int item = bid >> 1;
    int side = bid & 1;
    int t = threadIdx.x;

    const int* cA; const int* cB; int selfid; float* outp; bool isq;
    if (item < NB) {
        isq = true;
        cA = (side ? q_r1 : q_l1) + (size_t)item * MM * 2;
        cB = (side ? q_r2 : q_l2) + (size_t)item * MM * 2;
        selfid = query[item * 2 + side];
        outp = qv + (size_t)item * DM + side * D;
    } else {
        isq = false;
        int i2 = item - NB;
        cA = (side ? s_r1 : s_l1) + (size_t)i2 * MM * 2;
        cB = (side ? s_r2 : s_l2) + (size_t)i2 * MM * 2;
        selfid = support[i2 * 2 + side];
        outp = sv + (size_t)i2 * DM + side * D;
    }
    if (t < D) { aw[t] = attn_W[t]; gw[t] = gate_W[t]; }
    if (t < 2 * MM) {
        const int* c = (t < MM) ? cA : cB;
        int m = (t < MM) ? t : t - MM;
        rel[t] = c[m * 2]; ent[t] = c[m * 2 + 1];
    }
    __syncthreads();
    // gather + leakyrelu -> bf16 LDS, 16B loads
    for (int e8 = t; e8 < 2 * MM * 16; e8 += 256) {
        int m = e8 >> 4, d8 = (e8 & 15) * 8;
        short8 a = *(const short8*)(P1 + (size_t)rel[m] * D + d8);
        short8 b = *(const short8*)(P2 + (size_t)ent[m] * D + d8);
        short8 o;
        #pragma unroll
        for (int j = 0; j < 8; ++j) {
            float p = bf2f((unsigned short)a[j]) + bf2f((unsigned short)b[j]);
            p = (p >= 0.f) ? p : 0.01f * p;
            o[j] = (short)f2bf(p);
        }
        *(short8*)(proj + m * 136 + d8) = o;
    }
    __syncthreads();
    // scores: tab = t>>7, half g = (t>>6)&1, m = t&63 (m<50 valid)
    {
        int tab = t >> 7, g = (t >> 6) & 1, m = t & 63;
        float s = 0.f;
        if (m < MM) {
            const unsigned short* pr = proj + (tab * MM + m) * 136 + g * 64;
            #pragma unroll
            for (int i = 0; i < 8; ++i) {
                short8 v8 = *(const short8*)(pr + i * 8);
                #pragma unroll
                for (int j = 0; j < 8; ++j)
                    s += bf2f((unsigned short)v8[j]) * aw[g * 64 + i * 8 + j];
            }
        }
        scp[tab][g][m] = s;
    }
    __syncthreads();
    // softmax per table: wave 0 -> tabA, wave 1 -> tabB
    if (t < 128) {
        int tab = t >> 6, m = t & 63;
        float v = (m < MM) ? (scp[tab][0][m] + scp[tab][1][m] + attn_b[0]) : -1e30f;
        float mx = v;
        #pragma unroll
        for (int o = 32; o > 0; o >>= 1) mx = fmaxf(mx, __shfl_xor(mx, o, 64));
        float ev = (m < MM) ? __expf(v - mx) : 0.f;
        float sm = ev;
        #pragma unroll
        for (int o = 32; o > 0; o >>= 1) sm += __shfl_xor(sm, o, 64);
        if (m < MM) scw[tab * 64 + m] = ev / sm;
    }
    __syncthreads();
    // agg: tab = t>>7, d = t&127
    int tab = t >> 7, d = t & 127;
    float agg = 0.f;
    #pragma unroll 5
    for (int m = 0; m < MM; ++m)
        agg += scw[tab * 64 + m] * bf2f(proj[(tab * MM + m) * 136 + d]);
    // gate scalar per table (2 waves each)
    float gpart = agg * gw[d];
    #pragma unroll
    for (int o = 32; o > 0; o >>= 1) gpart += __shfl_xor(gpart, o, 64);
    if ((t & 63) == 0) redg[t >> 6] = gpart;
    __syncthreads();
    if (t == 0)  gateS[0] = sigf(redg[0] + redg[1] + gate_lb[0] + gate_b[0]);
    if (t == 64) gateS[1] = sigf(redg[2] + redg[3] + gate_lb[0] + gate_b[0]);
    __syncthreads();
    float embd = emb[(size_t)selfid * D + d];
    float val = gateS[tab] * agg + (1.f - gateS[tab]) * embd;
    if (tab == 1) oth[d] = val;
    __syncthreads();
    if (tab == 0) {
        float r = 0.5f * (val + oth[d]);
        outp[d] = r;
        if (isq) qvbf[(size_t)item * DM + side * D + d] = f2bf(r);
    }
}

// ---------------------------------------------------------------------------
// Kernel 3 (split): support vector -> sg.  k_sg1 (16 blocks) hid =
// relu(p1_W@s+b) AND zeroes d_out (4096 = 16*256, runs before mode-2
// atomics -- replaces k_zero launch).  k_sg2 (8 blocks) h = p2_W@hid + b + s,
// k_sg3 (1 block) layernorm.  float4 loads, shfl-group reductions.
// ---------------------------------------------------------------------------
__global__ __launch_bounds__(256) void k_sg1(
    const float* __restrict__ sv, const float* __restrict__ p1_W,
    const float* __restrict__ p1_b, float* __restrict__ hid,
    float* __restrict__ out)
{
    __shared__ float s[DM];
    int t = threadIdx.x;
    out[blockIdx.x * 256 + t] = 0.f;      // folded k_zero
    s[t] = sv[t];
    __syncthreads();
    int j = blockIdx.x * 32 + (t >> 3);   // 16 blocks * 32 rows = 512
    int pp = t & 7;                       // 8 lanes per row, 32 cols each
    const float* w = p1_W + (size_t)j * DM + pp * 32;
    float a = 0.f;
    #pragma unroll
    for (int i = 0; i < 8; ++i) {
        float4 v = *(const float4*)(w + i * 4);
        int c = pp * 32 + i * 4;
        a += v.x * s[c] + v.y * s[c + 1] + v.z * s[c + 2] + v.w * s[c + 3];
    }
    a += __shfl_xor(a, 1, 64);
    a += __shfl_xor(a, 2, 64);
    a += __shfl_xor(a, 4, 64);
    if (pp == 0) hid[j] = fmaxf(a + p1_b[j], 0.f);
}

__global__ __launch_bounds__(256) void k_sg2(
    const float* __restrict__ sv, const float* __restrict__ hid,
    const float* __restrict__ p2_W, const float* __restrict__ p2_b,
    float* __restrict__ h)
{
    __shared__ float hs[2 * DM];
    int t = threadIdx.x;
    hs[t] = hid[t]; hs[t + 256] = hid[t + 256];
    __syncthreads();
    int r = blockIdx.x * 32 + (t >> 3);   // 8 blocks * 32 rows = 256
    int pp = t & 7;                       // 8 lanes per row, 64 cols each
    const float* w = p2_W + (size_t)r * (2 * DM) + pp * 64;
    float a = 0.f;
    #pragma unroll
    for (int i = 0; i < 16; ++i) {
        float4 v = *(const float4*)(w + i * 4);
        int c = pp * 64 + i * 4;
        a += v.x * hs[c] + v.y * hs[c + 1] + v.z * hs[c + 2] + v.w * hs[c + 3];
    }
    a += __shfl_xor(a, 1, 64);
    a += __shfl_xor(a, 2, 64);
    a += __shfl_xor(a, 4, 64);
    if (pp == 0) h[r] = a + p2_b[r] + sv[r];
}

__global__ __launch_bounds__(256) void k_sg3(
    const float* __restrict__ h, const float* __restrict__ ln_a,
    const float* __restrict__ ln_b, float* __restrict__ sg)
{
    __shared__ float red[8];
    int t = threadIdx.x;
    float x = h[t];
    float sm = x;
    #pragma unroll
    for (int o = 32; o > 0; o >>= 1) sm += __shfl_xor(sm, o, 64);
    if ((t & 63) == 0) red[t >> 6] = sm;
    __syncthreads();
    float mu = (red[0] + red[1] + red[2] + red[3]) * (1.0f / 256.0f);
    float dv = x - mu;
    float sq = dv * dv;
    #pragma unroll
    for (int o = 32; o > 0; o >>= 1) sq += __shfl_xor(sq, o, 64);
    if ((t & 63) == 0) red[4 + (t >> 6)] = sq;
    __syncthreads();
    float var = (red[4] + red[5] + red[6] + red[7]) * (1.0f / 255.0f);  // ddof=1
    float sig = sqrtf(var);
    sg[t] = dv / (sig + 0.001f) * ln_a[t] + ln_b[t];
}

// ---------------------------------------------------------------------------
// Kernel 4: sgW[k] = sum_j sg[j] * Whh[k, 256+j]  (constant over batch)
// 32 blocks, 4 lanes per output row, float4 loads.
// ---------------------------------------------------------------------------
__global__ __launch_bounds__(256) void k_sgwhh(
    const float* __restrict__ sg, const float* __restrict__ Whh,
    float* __restrict__ sgW)
{
    __shared__ float s[DM];
    int t = threadIdx.x;
    s[t] = sg[t];
    __syncthreads();
    int k = blockIdx.x * 64 + (t >> 2);   // 32 blocks * 64 rows = 2048
    int pp = t & 3;                       // 4 lanes per row, 64 cols each
    const float* w = Whh + (size_t)k * HSZ + DM + pp * 64;
    float a = 0.f;
    #pragma unroll
    for (int i = 0; i < 16; ++i) {
        float4 v = *(const float4*)(w + i * 4);
        int c = pp * 64 + i * 4;
        a += v.x * s[c] + v.y * s[c + 1] + v.z * s[c + 2] + v.w * s[c + 3];
    }
    a += __shfl_xor(a, 1, 64);
    a += __shfl_xor(a, 2, 64);
    if (pp == 0) sgW[k] = a;
}

// ---------------------------------------------------------------------------
// Kernel 6: fused LSTM step via MFMA.  Block = 32 batch rows; wave w owns ONE
// column tile T = blockIdx.y*4 + w (grid y=8 for modes 0/1; y=4 for mode 2)
// plus its gate tiles T+32g -> all four gates of col k=T*16+nl in-wave.
// g0 and C live in MFMA-fragment layout (coalesced per-lane I/O).
// hq uses PING-PONG buffers across launches.
//   mode 0: A = qv(bf16), B = Wihp. g = A@B + gb; store g0f, Cf, hq->hqo.
//   mode 1: A = Ain,      B = Whhp. g = A@B + g0f + sgW; Cf; hq->hqo.
//   mode 2: like 1, no stores; atomicAdd dot(h, sg) into out.
// ---------------------------------------------------------------------------
__global__ __launch_bounds__(256, 4) void k_lstm(
    const float* __restrict__ qv, const unsigned short* __restrict__ Ain,
    const unsigned short* __restrict__ Bp,
    const float* __restrict__ gb, const float* __restrict__ sgW,
    const unsigned short* __restrict__ g0i, unsigned short* __restrict__ g0o,
    float4* __restrict__ Cf, unsigned short* __restrict__ hqo,
    const float* __restrict__ sg, float* __restrict__ out, int mode)
{
    int t = threadIdx.x;
    int lane = t & 63, w = t >> 6;
    int nl = lane & 15, quad = lane >> 4;
    int bx = blockIdx.x;
    int b0 = bx * 32;
    int T = blockIdx.y * 4 + w;

    floatx4 acc[2][4];
    #pragma unroll
    for (int mt = 0; mt < 2; ++mt)
        #pragma unroll
        for (int g = 0; g < 4; ++g) acc[mt][g] = (floatx4){0.f, 0.f, 0.f, 0.f};

    for (int ks = 0; ks < 8; ++ks) {
        short8 af0 = *(const short8*)(Ain + (size_t)(b0 + nl) * DM + ks * 32 + quad * 8);
        short8 af1 = *(const short8*)(Ain + (size_t)(b0 + 16 + nl) * DM + ks * 32 + quad * 8);
        #pragma unroll
        for (int g = 0; g < 4; ++g) {
            short8 bfr = *(const short8*)(Bp + ((size_t)((T + 32 * g) * 8 + ks) * 64 + lane) * 8);
            acc[0][g] = __builtin_amdgcn_mfma_f32_16x16x32_bf16(af0, bfr, acc[0][g], 0, 0, 0);
            acc[1][g] = __builtin_amdgcn_mfma_f32_16x16x32_bf16(af1, bfr, acc[1][g], 0, 0, 0);
        }
    }

    int coli = T * 16 + nl;
    float preg[2][4] = {{0.f, 0.f, 0.f, 0.f}, {0.f, 0.f, 0.f, 0.f}};
    #pragma unroll
    for (int mt = 0; mt < 2; ++mt) {
        size_t cfi = (((size_t)bx * 32 + T) * 2 + mt) * 64 + lane;
        if (mode == 0) {
            float bi = gb[coli], bff = gb[coli + 512];
            float bg = gb[coli + 1024], bo = gb[coli + 1536];
            float4 cn4; ushort4 pk[4];
            #pragma unroll
            for (int r = 0; r < 4; ++r) {
                float gi_ = acc[mt][0][r] + bi;
                float gf_ = acc[mt][1][r] + bff;
                float gg_ = acc[mt][2][r] + bg;
                float go_ = acc[mt][3][r] + bo;
                float cn = sigf(gi_) * tanhfast(gg_);
                (&cn4.x)[r] = cn;
                ((unsigned short*)&pk[0])[r] = f2bf(gi_);
                ((unsigned short*)&pk[1])[r] = f2bf(gf_);
                ((unsigned short*)&pk[2])[r] = f2bf(gg_);
                ((unsigned short*)&pk[3])[r] = f2bf(go_);
                if (T < 16) {
                    int b = b0 + mt * 16 + quad * 4 + r;
                    float h = qv[(size_t)b * DM + coli] + sigf(go_) * tanhfast(cn);
                    hqo[(size_t)b * DM + coli] = f2bf(h);
                }
            }
            #pragma unroll
            for (int g = 0; g < 4; ++g) {
                size_t gfi = ((((size_t)bx * 128 + g * 32 + T) * 2 + mt) * 64 + lane) * 4;
                *(ushort4*)(g0o + gfi) = pk[g];
            }
            Cf[cfi] = cn4;
        } else {
            float si = sgW[coli], sf = sgW[coli + 512];
            float sgg = sgW[coli + 1024], so = sgW[coli + 1536];
            ushort4 gld[4];
            #pragma unroll
            for (int g = 0; g < 4; ++g) {
                size_t gfi = ((((size_t)bx * 128 + g * 32 + T) * 2 + mt) * 64 + lane) * 4;
                gld[g] = *(const ushort4*)(g0i + gfi);
            }
            float4 cold = Cf[cfi];
            float4 cn4;
            #pragma unroll
            for (int r = 0; r < 4; ++r) {
                float gi_ = acc[mt][0][r] + si  + bf2f(((unsigned short*)&gld[0])[r]);
                float gf_ = acc[mt][1][r] + sf  + bf2f(((unsigned short*)&gld[1])[r]);
                float gg_ = acc[mt][2][r] + sgg + bf2f(((unsigned short*)&gld[2])[r]);
                float go_ = acc[mt][3][r] + so  + bf2f(((unsigned short*)&gld[3])[r]);
                float cn = sigf(gf_) * (&cold.x)[r] + sigf(gi_) * tanhfast(cn ? gg_ : gg_);
                cn = sigf(gf_) * (&cold.x)[r] + sigf(gi_) * tanhfast(gg_);
                (&cn4.x)[r] = cn;
                if (T < 16) {
                    int b = b0 + mt * 16 + quad * 4 + r;
                    float h = qv[(size_t)b * DM + coli] + sigf(go_) * tanhfast(cn);
                    if (mode == 1) hqo[(size_t)b * DM + coli] = f2bf(h);
                    else           preg[mt][r] += h * sg[coli];
                }
            }
            if (mode == 1) Cf[cfi] = cn4;
        }
    }

    if (mode == 2) {
        #pragma unroll
        for (int mt = 0; mt < 2; ++mt)
            #pragma unroll
            for (int r = 0; r < 4; ++r) {
                float p = preg[mt][r];
                p += __shfl_xor(p, 1, 64);
                p += __shfl_xor(p, 2, 64);
                p += __shfl_xor(p, 4, 64);
                p += __shfl_xor(p, 8, 64);
                if (nl == 0)
                    atomicAdd(out + b0 + mt * 16 + quad * 4 + r, p);
            }
    }
}

// ---------------------------------------------------------------------------
extern "C" void kernel_launch(void* const* d_in, const int* in_sizes, int n_in,
                              void* d_out, int out_size, void* d_ws, size_t ws_size,
                              hipStream_t stream) {
    const int* query   = (const int*)d_in[0];
    const int* support = (const int*)d_in[1];
    const int* q_l1 = (const int*)d_in[2];
    const int* q_l2 = (const int*)d_in[3];
    const int* q_r1 = (const int*)d_in[5];
    const int* q_r2 = (const int*)d_in[6];
    const int* s_l1 = (const int*)d_in[8];
    const int* s_l2 = (const int*)d_in[9];
    const int* s_r1 = (const int*)d_in[11];
    const int* s_r2 = (const int*)d_in[12];
    const float* emb    = (const float*)d_in[14];
    const float* gcn_W  = (const float*)d_in[15];
    const float* gcn_lb = (const float*)d_in[16];
    const float* gcn_b  = (const float*)d_in[17];
    const float* attn_W = (const float*)d_in[18];
    const float* attn_b = (const float*)d_in[19];
    const float* gate_W = (const float*)d_in[20];
    const float* gate_lb = (const float*)d_in[21];
    const float* gate_b  = (const float*)d_in[22];
    const float* p1_W = (const float*)d_in[23];
    const float* p1_b = (const float*)d_in[24];
    const float* p2_W = (const float*)d_in[25];
    const float* p2_b = (const float*)d_in[26];
    const float* ln_a = (const float*)d_in[27];
    const float* ln_b = (const float*)d_in[28];
    const float* Wih  = (const float*)d_in[29];
    const float* Whh  = (const float*)d_in[30];
    const float* bih  = (const float*)d_in[31];
    const float* bhh  = (const float*)d_in[32];

    // workspace layout: bf16 buffers first, then fp32 (16B-aligned blocks)
    unsigned short* P1   = (unsigned short*)d_ws;               // (V+1)*128
    unsigned short* P2   = P1 + (size_t)(VSZ + 1) * D;
    unsigned short* Wb   = P2 + (size_t)(VSZ + 1) * D;          // 256*128
    unsigned short* Wihp = Wb + 256 * 128;                      // 65536*8
    unsigned short* Whhp = Wihp + (size_t)65536 * 8;            // 65536*8
    unsigned short* g0b  = Whhp + (size_t)65536 * 8;            // NB*2048 (frag)
    unsigned short* hqA  = g0b + (size_t)NB * G4;               // NB*256
    unsigned short* hqB  = hqA + (size_t)NB * DM;               // NB*256
    unsigned short* qvbf = hqB + (size_t)NB * DM;               // NB*256
    float* fws = (float*)(qvbf + (size_t)NB * DM);
    float* gbv = fws;  fws += G4;
    float* qvb = fws;  fws += (size_t)NB * DM;                  // 4 MB
    float* svb = fws;  fws += DM;
    float* sgb = fws;  fws += DM;
    float* sgW = fws;  fws += G4 + 4;   // keep next block 16B-aligned
    float* hidb = fws; fws += 2 * DM;   // 512 (k_sg split intermediates)
    float* hb  = fws;  fws += DM;       // 256
    float4* Cf = (float4*)fws;  fws += (size_t)NB * HSZ;        // 8 MB (frag)
    (void)in_sizes; (void)n_in; (void)out_size; (void)ws_size;

    k_pack<<<648, 256, 0, stream>>>(
        Wih, Whh, bih, bhh, gcn_W, Wihp, Whhp, gbv, Wb);
    k_proj_mfma<<<(VSZ + 1 + 31) / 32, 256, 0, stream>>>(
        emb, Wb, gcn_lb, gcn_b, P1, P2, VSZ + 1);
    k_nbr<<<2 * (NB + 1), 256, 0, stream>>>(
        query, support, q_l1, q_l2, q_r1, q_r2, s_l1, s_l2, s_r1, s_r2,
        P1, P2, emb, attn_W, attn_b, gate_W, gate_lb, gate_b, qvb, qvbf, svb);
    k_sg1<<<16, 256, 0, stream>>>(svb, p1_W, p1_b, hidb, (float*)d_out);
    k_sg2<<<8, 256, 0, stream>>>(svb, hidb, p2_W, p2_b, hb);
    k_sg3<<<1, 256, 0, stream>>>(hb, ln_a, ln_b, sgb);
    k_sgwhh<<<32, 256, 0, stream>>>(sgb, Whh, sgW);
    // step 1 (h_r = 0): A = qv bf16, B = Wih; write hqA
    k_lstm<<<dim3(NB / 32, 8), 256, 0, stream>>>(
        qvb, qvbf, Wihp, gbv, sgW, g0b, g0b, Cf, hqA, sgb, (float*)d_out, 0);
    // step 2: read hqA, write hqB
    k_lstm<<<dim3(NB / 32, 8), 256, 0, stream>>>(
        qvb, hqA, Whhp, gbv, sgW, g0b, g0b, Cf, hqB, sgb, (float*)d_out, 1);
    // step 3: read hqB, write hqA
    k_lstm<<<dim3(NB / 32, 8), 256, 0, stream>>>(
        qvb, hqB, Whhp, gbv, sgW, g0b, g0b, Cf, hqA, sgb, (float*)d_out, 1);
    // step 4: read hqA; only cols < 256 matter -> y < 4; atomic dot into out
    k_lstm<<<dim3(NB / 32, 4), 256, 0, stream>>>(
        qvb, hqA, Whhp, gbv, sgW, g0b, g0b, Cf, hqB, sgb, (float*)d_out, 2);
}

// Round 6
// 378.501 us; speedup vs baseline: 1.1102x; 1.1102x over previous
//
#include <hip/hip_runtime.h>

// Problem constants (match reference)
#define D    128      // embedding dim
#define VSZ  200000   // vocab (emb has VSZ+1 rows, last row = 0)
#define NB   4096     // batch B
#define MM   50       // neighbors
#define DM   256      // 2*D
#define HSZ  512      // H
#define G4   2048     // 4*H

typedef __attribute__((ext_vector_type(8))) short short8;   // 8 bf16 = 4 VGPRs
typedef __attribute__((ext_vector_type(4))) float floatx4;  // MFMA acc

__device__ __forceinline__ float sigf(float x) { return 1.0f / (1.0f + __expf(-x)); }
__device__ __forceinline__ float tanhfast(float x) { return 1.0f - 2.0f / (__expf(2.0f * x) + 1.0f); }
__device__ __forceinline__ unsigned short f2bf(float x) {
    unsigned int u = __float_as_uint(x);
    u += 0x7FFFu + ((u >> 16) & 1u);   // round-to-nearest-even
    return (unsigned short)(u >> 16);
}
__device__ __forceinline__ float bf2f(unsigned short s) {
    return __uint_as_float(((unsigned int)s) << 16);
}

// async 16B global->LDS DMA (gfx950).  lds dest must be wave-uniform;
// HW writes dest + lane*16.  size must be a literal (4/12/16).
__device__ __forceinline__ void async_copy16(void* lds, const void* gsrc) {
    __builtin_amdgcn_global_load_lds(
        (const __attribute__((address_space(1))) unsigned int*)gsrc,
        (__attribute__((address_space(3))) unsigned int*)lds, 16, 0, 0);
}

// ---------------------------------------------------------------------------
// Kernel 0 (merged): pack Wih (2048x256) and Whh[:, :256] into fragment-linear
// bf16 (chunk idx = (tile*8+ks)*64+lane), gb = bih+bhh, AND repack gcn_W
// (128x256 fp32) into bf16 Wb[n][k].
// ---------------------------------------------------------------------------
__global__ __launch_bounds__(256) void k_pack(
    const float* __restrict__ Wih, const float* __restrict__ Whh,
    const float* __restrict__ bih, const float* __restrict__ bhh,
    const float* __restrict__ gcn_W,
    unsigned short* __restrict__ Wihp, unsigned short* __restrict__ Whhp,
    float* __restrict__ gb, unsigned short* __restrict__ Wb)
{
    int idx = blockIdx.x * 256 + threadIdx.x;
    if (idx < 131072) {
        int ci = idx & 65535;
        int lane = ci & 63, rest = ci >> 6;
        int ks = rest & 7, tile = rest >> 3;
        int n = tile * 16 + (lane & 15), k = ks * 32 + (lane >> 4) * 8;
        const float* src = (idx < 65536) ? (Wih + (size_t)n * 256 + k)
                                         : (Whh + (size_t)n * 512 + k);
        unsigned short* dst = (idx < 65536) ? Wihp : Whhp;
        short8 o;
        #pragma unroll
        for (int j = 0; j < 8; ++j) o[j] = (short)f2bf(src[j]);
        *(short8*)(dst + (size_t)ci * 8) = o;
    } else if (idx < 131072 + 2048) {
        int i = idx - 131072;
        gb[i] = bih[i] + bhh[i];
    } else if (idx < 131072 + 2048 + 32768) {
        int i = idx - (131072 + 2048);
        int n = i >> 7, k = i & 127;
        float v = (n < 128) ? gcn_W[n * 256 + k] : gcn_W[(n - 128) * 256 + 128 + k];
        Wb[i] = f2bf(v);
    }
}

// ---------------------------------------------------------------------------
// Kernel 1: P = emb @ Wcat^T via bf16 MFMA.  R3 structure (best measured:
// 80us, 2.17 TB/s).  Lever (R3 vs R4): in-flight DMA bytes/CU.  64-row
// blocks, 32KB fp32 A staged by global_load_lds (source pre-swizzled
// byte^=(row&7)<<5), MFMA reads swizzled fp32 + inline cvt, C staged in the
// same 33.8KB LDS union, 3 barriers, none after global stores.
// ---------------------------------------------------------------------------
__global__ __launch_bounds__(256, 4) void k_proj_mfma(
    const float* __restrict__ emb, const unsigned short* __restrict__ Wb,
    const float* __restrict__ gcn_lb, const float* __restrict__ gcn_b,
    unsigned short* __restrict__ P1, unsigned short* __restrict__ P2, int nrows)
{
    __shared__ unsigned short S[16896];   // 33792 B: A fp32 (32KB, swz) / C bf16
    int t = threadIdx.x;
    int v0 = blockIdx.x * 64;
    int lane = t & 63, w = t >> 6;
    int nl = lane & 15, quad = lane >> 4;
    int n0 = w * 64;

    // ---- stage A: 64 rows x 512 B via async DMA, source pre-swizzled ----
    #pragma unroll
    for (int it = 0; it < 8; ++it) {
        int chunk = w * 8 + it;
        int o = chunk * 1024 + lane * 16;         // linear LDS byte this lane fills
        int row = o >> 9;
        int b = o & 511;
        int bs = b ^ ((row & 7) << 5);            // inverse swizzle on source
        int v = v0 + row;
        v = (v < nrows) ? v : (nrows - 1);        // clamp tail (stores guarded)
        async_copy16((char*)S + chunk * 1024,
                     (const char*)emb + (size_t)v * 512 + bs);
    }
    __syncthreads();   // drains DMA (vmcnt 0) -- once per block, not per ks

    floatx4 acc[4][4];
    #pragma unroll
    for (int mt = 0; mt < 4; ++mt)
        #pragma unroll
        for (int nt = 0; nt < 4; ++nt)
            acc[mt][nt] = (floatx4){0.f, 0.f, 0.f, 0.f};

    const char* Sb = (const char*)S;
    #pragma unroll
    for (int ks = 0; ks < 4; ++ks) {
        short8 bfr[4];
        #pragma unroll
        for (int nt = 0; nt < 4; ++nt)
            bfr[nt] = *(const short8*)(Wb + (size_t)(n0 + nt * 16 + nl) * 128 + ks * 32 + quad * 8);
        short8 af[4];
        #pragma unroll
        for (int mt = 0; mt < 4; ++mt) {
            int row = mt * 16 + nl;
            int b = ks * 128 + quad * 32;
            int ba = row * 512 + (b ^ ((row & 7) << 5));   // swizzled read
            float4 lo = *(const float4*)(Sb + ba);
            float4 hi = *(const float4*)(Sb + ba + 16);
            short8 a;
            a[0] = (short)f2bf(lo.x); a[1] = (short)f2bf(lo.y);
            a[2] = (short)f2bf(lo.z); a[3] = (short)f2bf(lo.w);
            a[4] = (short)f2bf(hi.x); a[5] = (short)f2bf(hi.y);
            a[6] = (short)f2bf(hi.z); a[7] = (short)f2bf(hi.w);
            af[mt] = a;
        }
        #pragma unroll
        for (int mt = 0; mt < 4; ++mt)
            #pragma unroll
            for (int nt = 0; nt < 4; ++nt)
                acc[mt][nt] = __builtin_amdgcn_mfma_f32_16x16x32_bf16(
                    af[mt], bfr[nt], acc[mt][nt], 0, 0, 0);
    }

    __syncthreads();   // A consumed by ALL waves; reuse S as C (64 x 264 bf16)
    #pragma unroll
    for (int nt = 0; nt < 4; ++nt) {
        int col = n0 + nt * 16 + nl;
        float bias = (col < 128) ? (gcn_lb[col] + gcn_b[col]) : 0.f;
        #pragma unroll
        for (int mt = 0; mt < 4; ++mt)
            #pragma unroll
            for (int reg = 0; reg < 4; ++reg)
                S[(mt * 16 + quad * 4 + reg) * 264 + col] =
                    f2bf(acc[mt][nt][reg] + bias);
    }
    __syncthreads();
    #pragma unroll
    for (int it = 0; it < 8; ++it) {
        int c = t + 256 * it;
        int row = c >> 5, c8 = c & 31;
        int v = v0 + row;
        if (v < nrows) {
            int4 val = *(const int4*)(S + row * 264 + c8 * 8);
            unsigned short* dst = (c8 < 16) ? (P1 + (size_t)v * D + c8 * 8)
                                            : (P2 + (size_t)v * D + (c8 - 16) * 8);
            *(int4*)dst = val;
        }
    }
}

// ---------------------------------------------------------------------------
// Kernel 2: neighbor aggregation, both conn tables concurrently.
// One block per (item, side).  16B gathers (8 bf16 per load).
// ---------------------------------------------------------------------------
__global__ __launch_bounds__(256) void k_nbr(
    const int* __restrict__ query, const int* __restrict__ support,
    const int* __restrict__ q_l1, const int* __restrict__ q_l2,
    const int* __restrict__ q_r1, const int* __restrict__ q_r2,
    const int* __restrict__ s_l1, const int* __restrict__ s_l2,
    const int* __restrict__ s_r1, const int* __restrict__ s_r2,
    const unsigned short* __restrict__ P1, const unsigned short* __restrict__ P2,
    const float* __restrict__ emb,
    const float* __restrict__ attn_W, const float* __restrict__ attn_b,
    const float* __restrict__ gate_W, const float* __restrict__ gate_lb,
    const float* __restrict__ gate_b,
    float* __restrict__ qv, unsigned short* __restrict__ qvbf,
    float* __restrict__ sv)
{
    __shared__ unsigned short proj[2 * MM * 136];   // bf16, 27.2 KB
    __shared__ int rel[2 * MM], ent[2 * MM];
    __shared__ float scw[2 * 64];
    __shared__ float scp[2][2][64];
    __shared__ float aw[D], gw[D];
    __shared__ float redg[4];
    __shared__ float gateS[2];
    __shared__ float oth[D];

    int bid = blockIdx.x;
    int item = bid >> 1;
    int side = bid & 1;
    int t = threadIdx.x;

    const int* cA; const int* cB; int selfid; float* outp; bool isq;
    if (item < NB) {
        isq = true;
        cA = (side ? q_r1 : q_l1) + (size_t)item * MM * 2;
        cB = (side ? q_r2 : q_l2) + (size_t)item * MM * 2;
        selfid = query[item * 2 + side];
        outp = qv + (size_t)item * DM + side * D;
    } else {
        isq = false;
        int i2 = item - NB;
        cA = (side ? s_r1 : s_l1) + (size_t)i2 * MM * 2;
        cB = (side ? s_r2 : s_l2) + (size_t)i2 * MM * 2;
        selfid = support[i2 * 2 + side];
        outp = sv + (size_t)i2 * DM + side * D;
    }
    if (t < D) { aw[t] = attn_W[t]; gw[t] = gate_W[t]; }
    if (t < 2 * MM) {
        const int* c = (t < MM) ? cA : cB;
        int m = (t < MM) ? t : t - MM;
        rel[t] = c[m * 2]; ent[t] = c[m * 2 + 1];
    }
    __syncthreads();
    // gather + leakyrelu -> bf16 LDS, 16B loads
    for (int e8 = t; e8 < 2 * MM * 16; e8 += 256) {
        int m = e8 >> 4, d8 = (e8 & 15) * 8;
        short8 a = *(const short8*)(P1 + (size_t)rel[m] * D + d8);
        short8 b = *(const short8*)(P2 + (size_t)ent[m] * D + d8);
        short8 o;
        #pragma unroll
        for (int j = 0; j < 8; ++j) {
            float p = bf2f((unsigned short)a[j]) + bf2f((unsigned short)b[j]);
            p = (p >= 0.f) ? p : 0.01f * p;
            o[j] = (short)f2bf(p);
        }
        *(short8*)(proj + m * 136 + d8) = o;
    }
    __syncthreads();
    // scores: tab = t>>7, half g = (t>>6)&1, m = t&63 (m<50 valid)
    {
        int tab = t >> 7, g = (t >> 6) & 1, m = t & 63;
        float s = 0.f;
        if (m < MM) {
            const unsigned short* pr = proj + (tab * MM + m) * 136 + g * 64;
            #pragma unroll
            for (int i = 0; i < 8; ++i) {
                short8 v8 = *(const short8*)(pr + i * 8);
                #pragma unroll
                for (int j = 0; j < 8; ++j)
                    s += bf2f((unsigned short)v8[j]) * aw[g * 64 + i * 8 + j];
            }
        }
        scp[tab][g][m] = s;
    }
    __syncthreads();
    // softmax per table: wave 0 -> tabA, wave 1 -> tabB
    if (t < 128) {
        int tab = t >> 6, m = t & 63;
        float v = (m < MM) ? (scp[tab][0][m] + scp[tab][1][m] + attn_b[0]) : -1e30f;
        float mx = v;
        #pragma unroll
        for (int o = 32; o > 0; o >>= 1) mx = fmaxf(mx, __shfl_xor(mx, o, 64));
        float ev = (m < MM) ? __expf(v - mx) : 0.f;
        float sm = ev;
        #pragma unroll
        for (int o = 32; o > 0; o >>= 1) sm += __shfl_xor(sm, o, 64);
        if (m < MM) scw[tab * 64 + m] = ev / sm;
    }
    __syncthreads();
    // agg: tab = t>>7, d = t&127
    int tab = t >> 7, d = t & 127;
    float agg = 0.f;
    #pragma unroll 5
    for (int m = 0; m < MM; ++m)
        agg += scw[tab * 64 + m] * bf2f(proj[(tab * MM + m) * 136 + d]);
    // gate scalar per table (2 waves each)
    float gpart = agg * gw[d];
    #pragma unroll
    for (int o = 32; o > 0; o >>= 1) gpart += __shfl_xor(gpart, o, 64);
    if ((t & 63) == 0) redg[t >> 6] = gpart;
    __syncthreads();
    if (t == 0)  gateS[0] = sigf(redg[0] + redg[1] + gate_lb[0] + gate_b[0]);
    if (t == 64) gateS[1] = sigf(redg[2] + redg[3] + gate_lb[0] + gate_b[0]);
    __syncthreads();
    float embd = emb[(size_t)selfid * D + d];
    float val = gateS[tab] * agg + (1.f - gateS[tab]) * embd;
    if (tab == 1) oth[d] = val;
    __syncthreads();
    if (tab == 0) {
        float r = 0.5f * (val + oth[d]);
        outp[d] = r;
        if (isq) qvbf[(size_t)item * DM + side * D + d] = f2bf(r);
    }
}

// ---------------------------------------------------------------------------
// Kernel 3 (split): support vector -> sg.
// ---------------------------------------------------------------------------
__global__ __launch_bounds__(256) void k_sg1(
    const float* __restrict__ sv, const float* __restrict__ p1_W,
    const float* __restrict__ p1_b, float* __restrict__ hid)
{
    __shared__ float s[DM];
    int t = threadIdx.x;
    s[t] = sv[t];
    __syncthreads();
    int j = blockIdx.x * 32 + (t >> 3);   // 16 blocks * 32 rows = 512
    int pp = t & 7;                       // 8 lanes per row, 32 cols each
    const float* w = p1_W + (size_t)j * DM + pp * 32;
    float a = 0.f;
    #pragma unroll
    for (int i = 0; i < 8; ++i) {
        float4 v = *(const float4*)(w + i * 4);
        int c = pp * 32 + i * 4;
        a += v.x * s[c] + v.y * s[c + 1] + v.z * s[c + 2] + v.w * s[c + 3];
    }
    a += __shfl_xor(a, 1, 64);
    a += __shfl_xor(a, 2, 64);
    a += __shfl_xor(a, 4, 64);
    if (pp == 0) hid[j] = fmaxf(a + p1_b[j], 0.f);
}

__global__ __launch_bounds__(256) void k_sg2(
    const float* __restrict__ sv, const float* __restrict__ hid,
    const float* __restrict__ p2_W, const float* __restrict__ p2_b,
    float* __restrict__ h)
{
    __shared__ float hs[2 * DM];
    int t = threadIdx.x;
    hs[t] = hid[t]; hs[t + 256] = hid[t + 256];
    __syncthreads();
    int r = blockIdx.x * 32 + (t >> 3);   // 8 blocks * 32 rows = 256
    int pp = t & 7;                       // 8 lanes per row, 64 cols each
    const float* w = p2_W + (size_t)r * (2 * DM) + pp * 64;
    float a = 0.f;
    #pragma unroll
    for (int i = 0; i < 16; ++i) {
        float4 v = *(const float4*)(w + i * 4);
        int c = pp * 64 + i * 4;
        a += v.x * hs[c] + v.y * hs[c + 1] + v.z * hs[c + 2] + v.w * hs[c + 3];
    }
    a += __shfl_xor(a, 1, 64);
    a += __shfl_xor(a, 2, 64);
    a += __shfl_xor(a, 4, 64);
    if (pp == 0) h[r] = a + p2_b[r] + sv[r];
}

__global__ __launch_bounds__(256) void k_sg3(
    const float* __restrict__ h, const float* __restrict__ ln_a,
    const float* __restrict__ ln_b, float* __restrict__ sg)
{
    __shared__ float red[8];
    int t = threadIdx.x;
    float x = h[t];
    float sm = x;
    #pragma unroll
    for (int o = 32; o > 0; o >>= 1) sm += __shfl_xor(sm, o, 64);
    if ((t & 63) == 0) red[t >> 6] = sm;
    __syncthreads();
    float mu = (red[0] + red[1] + red[2] + red[3]) * (1.0f / 256.0f);
    float dv = x - mu;
    float sq = dv * dv;
    #pragma unroll
    for (int o = 32; o > 0; o >>= 1) sq += __shfl_xor(sq, o, 64);
    if ((t & 63) == 0) red[4 + (t >> 6)] = sq;
    __syncthreads();
    float var = (red[4] + red[5] + red[6] + red[7]) * (1.0f / 255.0f);  // ddof=1
    float sig = sqrtf(var);
    sg[t] = dv / (sig + 0.001f) * ln_a[t] + ln_b[t];
}

// ---------------------------------------------------------------------------
// Kernel 4: sgW[k] = sum_j sg[j] * Whh[k, 256+j]  (constant over batch).
// Only k with (k mod 512) < 256 are ever used downstream (dead-half trim),
// but computing all 2048 is cheap; keep full for simplicity.
// ---------------------------------------------------------------------------
__global__ __launch_bounds__(256) void k_sgwhh(
    const float* __restrict__ sg, const float* __restrict__ Whh,
    float* __restrict__ sgW)
{
    __shared__ float s[DM];
    int t = threadIdx.x;
    s[t] = sg[t];
    __syncthreads();
    int k = blockIdx.x * 64 + (t >> 2);   // 32 blocks * 64 rows = 2048
    int pp = t & 3;                       // 4 lanes per row, 64 cols each
    const float* w = Whh + (size_t)k * HSZ + DM + pp * 64;
    float a = 0.f;
    #pragma unroll
    for (int i = 0; i < 16; ++i) {
        float4 v = *(const float4*)(w + i * 4);
        int c = pp * 64 + i * 4;
        a += v.x * s[c] + v.y * s[c + 1] + v.z * s[c + 2] + v.w * s[c + 3];
    }
    a += __shfl_xor(a, 1, 64);
    a += __shfl_xor(a, 2, 64);
    if (pp == 0) sgW[k] = a;
}

// ---------------------------------------------------------------------------
// Kernel 5 (round-11): FULLY FUSED 4-step LSTM, dead-half trimmed.
// Key algebra: h_r = [hq, r] with r == sg (const, folded into sgW), so each
// step's A is hq only (256 cols); and hq = qv + hh[:, :DM] means gate/c
// columns >= 256 NEVER influence the output (c elementwise; hh[:, :256]
// needs only c[:, :256]).  The old 4-launch path computed+stored that half.
// Here: block = 16 batch rows, 512 threads (8 waves), grid 256.  Wave w owns
// H-col tiles kt = {w, w+8} (cols w*16.. and (w+8)*16.. => tiles 0..15 =
// cols 0..255 across 8 waves) for ALL FOUR gates -> c-update fully in-wave.
// hq passes between steps via an 8.4 KB LDS bf16 A-buffer.  g0 bf16-packed
// (16 VGPRs), c fp32 (8 VGPRs); ~126 VGPR total, no global g0/Cf/hq traffic,
// no atomics (plain stores; no d_out zeroing needed).  Math identical to the
// 4-launch path (g0 bf16, c fp32, hq bf16, fp32 qv in h-add).
// Tripwires: scratch => spill; wrong result => dead-half analysis wrong.
// ---------------------------------------------------------------------------
__global__ __launch_bounds__(512, 2) void k_lstm_fused(
    const float* __restrict__ qv, const unsigned short* __restrict__ qvbf,
    const unsigned short* __restrict__ Wihp, const unsigned short* __restrict__ Whhp,
    const float* __restrict__ gb, const float* __restrict__ sgW,
    const float* __restrict__ sg, float* __restrict__ out)
{
    __shared__ unsigned short Ab[16 * 264];    // 8448 B, hq tile between steps
    __shared__ float redbuf[8][16];
    int t = threadIdx.x;
    int lane = t & 63, w = t >> 6;
    int nl = lane & 15, quad = lane >> 4;
    int b0 = blockIdx.x * 16;

    // fill A with qvbf rows (step-1 input); 512 threads x 1 int4 = 16x256
    {
        int row = t >> 5, c16 = t & 31;
        *(int4*)(Ab + row * 264 + c16 * 8) =
            *(const int4*)(qvbf + (size_t)(b0 + row) * DM + c16 * 8);
    }
    int kt[2] = { w, w + 8 };              // this wave's H-col tiles (<16)

    float sgWreg[2][4], qvreg[2][4], sgreg2[2];
    float cc[2][4];                        // c state, fp32
    ushort4 g0s[2][4];                     // g0 state, bf16 packed
    #pragma unroll
    for (int j = 0; j < 2; ++j) {
        #pragma unroll
        for (int g = 0; g < 4; ++g)
            sgWreg[j][g] = sgW[g * 512 + kt[j] * 16 + nl];
        sgreg2[j] = sg[kt[j] * 16 + nl];
        #pragma unroll
        for (int r = 0; r < 4; ++r)
            qvreg[j][r] = qv[(size_t)(b0 + quad * 4 + r) * DM + kt[j] * 16 + nl];
    }
    __syncthreads();

    // ---- steps 1..3 (write hq back to Ab) ----
    #pragma unroll 1
    for (int st = 0; st < 3; ++st) {
        short8 af[8];
        #pragma unroll
        for (int ks = 0; ks < 8; ++ks)
            af[ks] = *(const short8*)(Ab + nl * 264 + ks * 32 + quad * 8);
        const unsigned short* Bp = (st == 0) ? Wihp : Whhp;
        floatx4 acc[2][4];
        #pragma unroll
        for (int j = 0; j < 2; ++j)
            #pragma unroll
            for (int g = 0; g < 4; ++g)
                acc[j][g] = (floatx4){0.f, 0.f, 0.f, 0.f};
        #pragma unroll
        for (int j = 0; j < 2; ++j)
            #pragma unroll
            for (int g = 0; g < 4; ++g) {
                int T = g * 32 + kt[j];
                #pragma unroll
                for (int ks = 0; ks < 8; ++ks) {
                    short8 bfr = *(const short8*)(Bp + ((size_t)(T * 8 + ks) * 64 + lane) * 8);
                    acc[j][g] = __builtin_amdgcn_mfma_f32_16x16x32_bf16(
                        af[ks], bfr, acc[j][g], 0, 0, 0);
                }
            }
        float hval[2][4];
        if (st == 0) {
            #pragma unroll
            for (int j = 0; j < 2; ++j) {
                float bi  = gb[0 * 512 + kt[j] * 16 + nl];
                float bf_ = gb[1 * 512 + kt[j] * 16 + nl];
                float bg  = gb[2 * 512 + kt[j] * 16 + nl];
                float bo  = gb[3 * 512 + kt[j] * 16 + nl];
                #pragma unroll
                for (int r = 0; r < 4; ++r) {
                    float gi_ = acc[j][0][r] + bi;
                    float gf_ = acc[j][1][r] + bf_;
                    float gg_ = acc[j][2][r] + bg;
                    float go_ = acc[j][3][r] + bo;
                    ((unsigned short*)&g0s[j][0])[r] = f2bf(gi_);
                    ((unsigned short*)&g0s[j][1])[r] = f2bf(gf_);
                    ((unsigned short*)&g0s[j][2])[r] = f2bf(gg_);
                    ((unsigned short*)&g0s[j][3])[r] = f2bf(go_);
                    float cn = sigf(gi_) * tanhfast(gg_);
                    cc[j][r] = cn;
                    hval[j][r] = qvreg[j][r] + sigf(go_) * tanhfast(cn);
                }
            }
        } else {
            #pragma unroll
            for (int j = 0; j < 2; ++j)
                #pragma unroll
                for (int r = 0; r < 4; ++r) {
                    float gi_ = acc[j][0][r] + sgWreg[j][0] + bf2f(((unsigned short*)&g0s[j][0])[r]);
                    float gf_ = acc[j][1][r] + sgWreg[j][1] + bf2f(((unsigned short*)&g0s[j][1])[r]);
                    float gg_ = acc[j][2][r] + sgWreg[j][2] + bf2f(((unsigned short*)&g0s[j][2])[r]);
                    float go_ = acc[j][3][r] + sgWreg[j][3] + bf2f(((unsigned short*)&g0s[j][3])[r]);
                    float cn = sigf(gf_) * cc[j][r] + sigf(gi_) * tanhfast(gg_);
                    cc[j][r] = cn;
                    hval[j][r] = qvreg[j][r] + sigf(go_) * tanhfast(cn);
                }
        }
        __syncthreads();   // all waves done READING Ab
        #pragma unroll
        for (int j = 0; j < 2; ++j)
            #pragma unroll
            for (int r = 0; r < 4; ++r)
                Ab[(quad * 4 + r) * 264 + kt[j] * 16 + nl] = f2bf(hval[j][r]);
        __syncthreads();   // writes visible
    }

    // ---- step 4: dot(hq4, sg) into out ----
    {
        short8 af[8];
        #pragma unroll
        for (int ks = 0; ks < 8; ++ks)
            af[ks] = *(const short8*)(Ab + nl * 264 + ks * 32 + quad * 8);
        floatx4 acc[2][4];
        #pragma unroll
        for (int j = 0; j < 2; ++j)
            #pragma unroll
            for (int g = 0; g < 4; ++g)
                acc[j][g] = (floatx4){0.f, 0.f, 0.f, 0.f};
        #pragma unroll
        for (int j = 0; j < 2; ++j)
            #pragma unroll
            for (int g = 0; g < 4; ++g) {
                int T = g * 32 + kt[j];
                #pragma unroll
                for (int ks = 0; ks < 8; ++ks) {
                    short8 bfr = *(const short8*)(Whhp + ((size_t)(T * 8 + ks) * 64 + lane) * 8);
                    acc[j][g] = __builtin_amdgcn_mfma_f32_16x16x32_bf16(
                        af[ks], bfr, acc[j][g], 0, 0, 0);
                }
            }
        float part[4] = {0.f, 0.f, 0.f, 0.f};
        #pragma unroll
        for (int j = 0; j < 2; ++j)
            #pragma unroll
            for (int r = 0; r < 4; ++r) {
                float gi_ = acc[j][0][r] + sgWreg[j][0] + bf2f(((unsigned short*)&g0s[j][0])[r]);
                float gf_ = acc[j][1][r] + sgWreg[j][1] + bf2f(((unsigned short*)&g0s[j][1])[r]);
                float gg_ = acc[j][2][r] + sgWreg[j][2] + bf2f(((unsigned short*)&g0s[j][2])[r]);
                float go_ = acc[j][3][r] + sgWreg[j][3] + bf2f(((unsigned short*)&g0s[j][3])[r]);
                float cn = sigf(gf_) * cc[j][r] + sigf(gi_) * tanhfast(gg_);
                float h = qvreg[j][r] + sigf(go_) * tanhfast(cn);
                part[r] += h * sgreg2[j];
            }
        #pragma unroll
        for (int r = 0; r < 4; ++r) {
            float p = part[r];
            p += __shfl_xor(p, 1, 64);
            p += __shfl_xor(p, 2, 64);
            p += __shfl_xor(p, 4, 64);
            p += __shfl_xor(p, 8, 64);
            if (nl == 0) redbuf[w][quad * 4 + r] = p;
        }
    }
    __syncthreads();
    if (t < 16) {
        float s = 0.f;
        #pragma unroll
        for (int w2 = 0; w2 < 8; ++w2) s += redbuf[w2][t];
        out[b0 + t] = s;
    }
}

// ---------------------------------------------------------------------------
extern "C" void kernel_launch(void* const* d_in, const int* in_sizes, int n_in,
                              void* d_out, int out_size, void* d_ws, size_t ws_size,
                              hipStream_t stream) {
    const int* query   = (const int*)d_in[0];
    const int* support = (const int*)d_in[1];
    const int* q_l1 = (const int*)d_in[2];
    const int* q_l2 = (const int*)d_in[3];
    const int* q_r1 = (const int*)d_in[5];
    const int* q_r2 = (const int*)d_in[6];
    const int* s_l1 = (const int*)d_in[8];
    const int* s_l2 = (const int*)d_in[9];
    const int* s_r1 = (const int*)d_in[11];
    const int* s_r2 = (const int*)d_in[12];
    const float* emb    = (const float*)d_in[14];
    const float* gcn_W  = (const float*)d_in[15];
    const float* gcn_lb = (const float*)d_in[16];
    const float* gcn_b  = (const float*)d_in[17];
    const float* attn_W = (const float*)d_in[18];
    const float* attn_b = (const float*)d_in[19];
    const float* gate_W = (const float*)d_in[20];
    const float* gate_lb = (const float*)d_in[21];
    const float* gate_b  = (const float*)d_in[22];
    const float* p1_W = (const float*)d_in[23];
    const float* p1_b = (const float*)d_in[24];
    const float* p2_W = (const float*)d_in[25];
    const float* p2_b = (const float*)d_in[26];
    const float* ln_a = (const float*)d_in[27];
    const float* ln_b = (const float*)d_in[28];
    const float* Wih  = (const float*)d_in[29];
    const float* Whh  = (const float*)d_in[30];
    const float* bih  = (const float*)d_in[31];
    const float* bhh  = (const float*)d_in[32];

    // workspace layout: bf16 buffers first, then fp32 (16B-aligned blocks)
    unsigned short* P1   = (unsigned short*)d_ws;               // (V+1)*128
    unsigned short* P2   = P1 + (size_t)(VSZ + 1) * D;
    unsigned short* Wb   = P2 + (size_t)(VSZ + 1) * D;          // 256*128
    unsigned short* Wihp = Wb + 256 * 128;                      // 65536*8
    unsigned short* Whhp = Wihp + (size_t)65536 * 8;            // 65536*8
    unsigned short* qvbf = Whhp + (size_t)65536 * 8;            // NB*256
    float* fws = (float*)(qvbf + (size_t)NB * DM);
    float* gbv = fws;  fws += G4;
    float* qvb = fws;  fws += (size_t)NB * DM;                  // 4 MB
    float* svb = fws;  fws += DM;
    float* sgb = fws;  fws += DM;
    float* sgW = fws;  fws += G4 + 4;   // keep next block 16B-aligned
    float* hidb = fws; fws += 2 * DM;   // 512
    float* hb  = fws;  fws += DM;       // 256
    (void)in_sizes; (void)n_in; (void)out_size; (void)ws_size;

    k_pack<<<648, 256, 0, stream>>>(
        Wih, Whh, bih, bhh, gcn_W, Wihp, Whhp, gbv, Wb);
    k_proj_mfma<<<(VSZ + 1 + 63) / 64, 256, 0, stream>>>(
        emb, Wb, gcn_lb, gcn_b, P1, P2, VSZ + 1);
    k_nbr<<<2 * (NB + 1), 256, 0, stream>>>(
        query, support, q_l1, q_l2, q_r1, q_r2, s_l1, s_l2, s_r1, s_r2,
        P1, P2, emb, attn_W, attn_b, gate_W, gate_lb, gate_b, qvb, qvbf, svb);
    k_sg1<<<16, 256, 0, stream>>>(svb, p1_W, p1_b, hidb);
    k_sg2<<<8, 256, 0, stream>>>(svb, hidb, p2_W, p2_b, hb);
    k_sg3<<<1, 256, 0, stream>>>(hb, ln_a, ln_b, sgb);
    k_sgwhh<<<32, 256, 0, stream>>>(sgb, Whh, sgW);
    k_lstm_fused<<<256, 512, 0, stream>>>(
        qvb, qvbf, Wihp, Whhp, gbv, sgW, sgb, (float*)d_out);
}

// Round 7
// 360.109 us; speedup vs baseline: 1.1669x; 1.0511x over previous
//
#include <hip/hip_runtime.h>

// Problem constants (match reference)
#define D    128      // embedding dim
#define VSZ  200000   // vocab (emb has VSZ+1 rows, last row = 0)
#define NB   4096     // batch B
#define MM   50       // neighbors
#define DM   256      // 2*D
#define HSZ  512      // H
#define G4   2048     // 4*H

typedef __attribute__((ext_vector_type(8))) short short8;   // 8 bf16 = 4 VGPRs
typedef __attribute__((ext_vector_type(4))) float floatx4;  // MFMA acc

__device__ __forceinline__ float sigf(float x) { return 1.0f / (1.0f + __expf(-x)); }
__device__ __forceinline__ float tanhfast(float x) { return 1.0f - 2.0f / (__expf(2.0f * x) + 1.0f); }
__device__ __forceinline__ unsigned short f2bf(float x) {
    unsigned int u = __float_as_uint(x);
    u += 0x7FFFu + ((u >> 16) & 1u);   // round-to-nearest-even
    return (unsigned short)(u >> 16);
}
__device__ __forceinline__ float bf2f(unsigned short s) {
    return __uint_as_float(((unsigned int)s) << 16);
}

// async 16B global->LDS DMA (gfx950).  lds dest must be wave-uniform;
// HW writes dest + lane*16.  size must be a literal (4/12/16).
__device__ __forceinline__ void async_copy16(void* lds, const void* gsrc) {
    __builtin_amdgcn_global_load_lds(
        (const __attribute__((address_space(1))) unsigned int*)gsrc,
        (__attribute__((address_space(3))) unsigned int*)lds, 16, 0, 0);
}

// ---------------------------------------------------------------------------
// Kernel 0 (merged): pack Wih (2048x256) and Whh[:, :256] into fragment-linear
// bf16 (chunk idx = (tile*8+ks)*64+lane), gb = bih+bhh, AND repack gcn_W
// (128x256 fp32) into bf16 Wb[n][k].
// ---------------------------------------------------------------------------
__global__ __launch_bounds__(256) void k_pack(
    const float* __restrict__ Wih, const float* __restrict__ Whh,
    const float* __restrict__ bih, const float* __restrict__ bhh,
    const float* __restrict__ gcn_W,
    unsigned short* __restrict__ Wihp, unsigned short* __restrict__ Whhp,
    float* __restrict__ gb, unsigned short* __restrict__ Wb)
{
    int idx = blockIdx.x * 256 + threadIdx.x;
    if (idx < 131072) {
        int ci = idx & 65535;
        int lane = ci & 63, rest = ci >> 6;
        int ks = rest & 7, tile = rest >> 3;
        int n = tile * 16 + (lane & 15), k = ks * 32 + (lane >> 4) * 8;
        const float* src = (idx < 65536) ? (Wih + (size_t)n * 256 + k)
                                         : (Whh + (size_t)n * 512 + k);
        unsigned short* dst = (idx < 65536) ? Wihp : Whhp;
        short8 o;
        #pragma unroll
        for (int j = 0; j < 8; ++j) o[j] = (short)f2bf(src[j]);
        *(short8*)(dst + (size_t)ci * 8) = o;
    } else if (idx < 131072 + 2048) {
        int i = idx - 131072;
        gb[i] = bih[i] + bhh[i];
    } else if (idx < 131072 + 2048 + 32768) {
        int i = idx - (131072 + 2048);
        int n = i >> 7, k = i & 127;
        float v = (n < 128) ? gcn_W[n * 256 + k] : gcn_W[(n - 128) * 256 + 128 + k];
        Wb[i] = f2bf(v);
    }
}

// ---------------------------------------------------------------------------
// Kernel 1: P = emb @ Wcat^T via bf16 MFMA.  Round-12: software-pipelined
// grid-stride loop (m201/T3+T4 pattern).  Diagnosis: R3's 2.2 TB/s cap is a
// DUTY-CYCLE problem -- all resident blocks stage together, barrier, compute
// together (HBM idle), exit together.  Now 768 blocks (3/CU) iterate ~8
// 32-row tiles each with double-buffered 16KB LDS: prefetch tile+G, counted
// s_waitcnt vmcnt(8) (4 prefetch DMA + 4 epilogue stores stay in flight),
// raw s_barrier (+sched_barrier fences, rule 18), MFMA, C-write, lgkmcnt-only
// barrier (prefetch NEVER drained), stores.  Wb fragments hoisted (64 VGPR;
// 3 waves/SIMD allows 170).  Source keeps the byte^=(row&7)<<5 pre-swizzle,
// reads swizzled (R3/R4-verified).  Tripwires: dur>=75us => theory dead,
// k_proj structurally capped, pivot to k_nbr; WRITE>>113MB => spill.
// ---------------------------------------------------------------------------
__global__ __launch_bounds__(256, 3) void k_proj_mfma(
    const float* __restrict__ emb, const unsigned short* __restrict__ Wb,
    const float* __restrict__ gcn_lb, const float* __restrict__ gcn_b,
    unsigned short* __restrict__ P1, unsigned short* __restrict__ P2, int nrows)
{
    __shared__ __align__(16) unsigned char Buf[2][16384];   // fp32 A, swizzled
    __shared__ unsigned short C[32 * 264];                  // 16896 B
    int t = threadIdx.x;
    int lane = t & 63, w = t >> 6;
    int nl = lane & 15, quad = lane >> 4;
    int n0 = w * 64;
    int G = gridDim.x;
    int ntile = (nrows + 31) >> 5;

    auto STAGE = [&](int pb, int tile) {
        int v0 = tile * 32;
        #pragma unroll
        for (int it = 0; it < 4; ++it) {
            int chunk = w * 4 + it;                // 16 chunks of 1KB
            int o = chunk * 1024 + lane * 16;      // linear LDS byte
            int row = o >> 9;
            int b = o & 511;
            int bs = b ^ ((row & 7) << 5);         // inverse swizzle on source
            int v = v0 + row;
            v = (v < nrows) ? v : (nrows - 1);     // clamp tail (stores guarded)
            async_copy16(Buf[pb] + chunk * 1024,
                         (const char*)emb + (size_t)v * 512 + bs);
        }
    };

    // hoist Wb fragments once: L2-resident, reused for every tile
    short8 bfr[4][4];
    #pragma unroll
    for (int nt = 0; nt < 4; ++nt)
        #pragma unroll
        for (int ks = 0; ks < 4; ++ks)
            bfr[nt][ks] = *(const short8*)(Wb + (size_t)(n0 + nt * 16 + nl) * 128 + ks * 32 + quad * 8);

    STAGE(0, blockIdx.x);                          // prologue
    int pb = 0;
    bool first = true;
    for (int tile = blockIdx.x; tile < ntile; tile += G) {
        int nxt = tile + G;
        bool pf = (nxt < ntile);
        if (pf) STAGE(pb ^ 1, nxt);
        // counted wait: newest (4 prefetch [+4 stores after iter 0]) may stay
        // outstanding; everything older (current buffer's DMA) must be done.
        if (first) {
            if (pf) asm volatile("s_waitcnt vmcnt(4)" ::: "memory");
            else    asm volatile("s_waitcnt vmcnt(0)" ::: "memory");
        } else {
            if (pf) asm volatile("s_waitcnt vmcnt(8)" ::: "memory");
            else    asm volatile("s_waitcnt vmcnt(4)" ::: "memory");
        }
        __builtin_amdgcn_sched_barrier(0);
        __builtin_amdgcn_s_barrier();
        __builtin_amdgcn_sched_barrier(0);

        // ---- compute 32-row tile from Buf[pb] ----
        floatx4 acc[2][4];
        #pragma unroll
        for (int mt = 0; mt < 2; ++mt)
            #pragma unroll
            for (int nt = 0; nt < 4; ++nt)
                acc[mt][nt] = (floatx4){0.f, 0.f, 0.f, 0.f};
        const char* Sb = (const char*)Buf[pb];
        #pragma unroll
        for (int ks = 0; ks < 4; ++ks) {
            short8 af[2];
            #pragma unroll
            for (int mt = 0; mt < 2; ++mt) {
                int row = mt * 16 + nl;
                int b = ks * 128 + quad * 32;
                int ba = row * 512 + (b ^ ((row & 7) << 5));   // swizzled read
                float4 lo = *(const float4*)(Sb + ba);
                float4 hi = *(const float4*)(Sb + ba + 16);
                short8 a;
                a[0] = (short)f2bf(lo.x); a[1] = (short)f2bf(lo.y);
                a[2] = (short)f2bf(lo.z); a[3] = (short)f2bf(lo.w);
                a[4] = (short)f2bf(hi.x); a[5] = (short)f2bf(hi.y);
                a[6] = (short)f2bf(hi.z); a[7] = (short)f2bf(hi.w);
                af[mt] = a;
            }
            #pragma unroll
            for (int mt = 0; mt < 2; ++mt)
                #pragma unroll
                for (int nt = 0; nt < 4; ++nt)
                    acc[mt][nt] = __builtin_amdgcn_mfma_f32_16x16x32_bf16(
                        af[mt], bfr[nt][ks], acc[mt][nt], 0, 0, 0);
        }

        // ---- C-stage (bf16) ----
        #pragma unroll
        for (int nt = 0; nt < 4; ++nt) {
            int col = n0 + nt * 16 + nl;
            float bias = (col < 128) ? (gcn_lb[col] + gcn_b[col]) : 0.f;
            #pragma unroll
            for (int mt = 0; mt < 2; ++mt)
                #pragma unroll
                for (int reg = 0; reg < 4; ++reg)
                    C[(mt * 16 + quad * 4 + reg) * 264 + col] =
                        f2bf(acc[mt][nt][reg] + bias);
        }
        // lgkm-only barrier: C visible + Buf[pb] reads retired, WITHOUT
        // draining the in-flight prefetch (no vmcnt here).
        asm volatile("s_waitcnt lgkmcnt(0)" ::: "memory");
        __builtin_amdgcn_sched_barrier(0);
        __builtin_amdgcn_s_barrier();
        __builtin_amdgcn_sched_barrier(0);

        // ---- coalesced stores: 1024 16B chunks ----
        #pragma unroll
        for (int it = 0; it < 4; ++it) {
            int c = t + 256 * it;
            int row = c >> 5, c8 = c & 31;
            int v = tile * 32 + row;
            if (v < nrows) {
                int4 val = *(const int4*)(C + row * 264 + c8 * 8);
                unsigned short* dst = (c8 < 16) ? (P1 + (size_t)v * D + c8 * 8)
                                                : (P2 + (size_t)v * D + (c8 - 16) * 8);
                *(int4*)dst = val;
            }
        }
        pb ^= 1;
        first = false;
    }
}

// ---------------------------------------------------------------------------
// Kernel 2: neighbor aggregation, both conn tables concurrently.
// One block per (item, side).  16B gathers (8 bf16 per load).
// ---------------------------------------------------------------------------
__global__ __launch_bounds__(256) void k_nbr(
    const int* __restrict__ query, const int* __restrict__ support,
    const int* __restrict__ q_l1, const int* __restrict__ q_l2,
    const int* __restrict__ q_r1, const int* __restrict__ q_r2,
    const int* __restrict__ s_l1, const int* __restrict__ s_l2,
    const int* __restrict__ s_r1, const int* __restrict__ s_r2,
    const unsigned short* __restrict__ P1, const unsigned short* __restrict__ P2,
    const float* __restrict__ emb,
    const float* __restrict__ attn_W, const float* __restrict__ attn_b,
    const float* __restrict__ gate_W, const float* __restrict__ gate_lb,
    const float* __restrict__ gate_b,
    float* __restrict__ qv, unsigned short* __restrict__ qvbf,
    float* __restrict__ sv)
{
    __shared__ unsigned short proj[2 * MM * 136];   // bf16, 27.2 KB
    __shared__ int rel[2 * MM], ent[2 * MM];
    __shared__ float scw[2 * 64];
    __shared__ float scp[2][2][64];
    __shared__ float aw[D], gw[D];
    __shared__ float redg[4];
    __shared__ float gateS[2];
    __shared__ float oth[D];

    int bid = blockIdx.x;
    int item = bid >> 1;
    int side = bid & 1;
    int t = threadIdx.x;

    const int* cA; const int* cB; int selfid; float* outp; bool isq;
    if (item < NB) {
        isq = true;
        cA = (side ? q_r1 : q_l1) + (size_t)item * MM * 2;
        cB = (side ? q_r2 : q_l2) + (size_t)item * MM * 2;
        selfid = query[item * 2 + side];
        outp = qv + (size_t)item * DM + side * D;
    } else {
        isq = false;
        int i2 = item - NB;
        cA = (side ? s_r1 : s_l1) + (size_t)i2 * MM * 2;
        cB = (side ? s_r2 : s_l2) + (size_t)i2 * MM * 2;
        selfid = support[i2 * 2 + side];
        outp = sv + (size_t)i2 * DM + side * D;
    }
    if (t < D) { aw[t] = attn_W[t]; gw[t] = gate_W[t]; }
    if (t < 2 * MM) {
        const int* c = (t < MM) ? cA : cB;
        int m = (t < MM) ? t : t - MM;
        rel[t] = c[m * 2]; ent[t] = c[m * 2 + 1];
    }
    __syncthreads();
    // gather + leakyrelu -> bf16 LDS, 16B loads
    for (int e8 = t; e8 < 2 * MM * 16; e8 += 256) {
        int m = e8 >> 4, d8 = (e8 & 15) * 8;
        short8 a = *(const short8*)(P1 + (size_t)rel[m] * D + d8);
        short8 b = *(const short8*)(P2 + (size_t)ent[m] * D + d8);
        short8 o;
        #pragma unroll
        for (int j = 0; j < 8; ++j) {
            float p = bf2f((unsigned short)a[j]) + bf2f((unsigned short)b[j]);
            p = (p >= 0.f) ? p : 0.01f * p;
            o[j] = (short)f2bf(p);
        }
        *(short8*)(proj + m * 136 + d8) = o;
    }
    __syncthreads();
    // scores: tab = t>>7, half g = (t>>6)&1, m = t&63 (m<50 valid)
    {
        int tab = t >> 7, g = (t >> 6) & 1, m = t & 63;
        float s = 0.f;
        if (m < MM) {
            const unsigned short* pr = proj + (tab * MM + m) * 136 + g * 64;
            #pragma unroll
            for (int i = 0; i < 8; ++i) {
                short8 v8 = *(const short8*)(pr + i * 8);
                #pragma unroll
                for (int j = 0; j < 8; ++j)
                    s += bf2f((unsigned short)v8[j]) * aw[g * 64 + i * 8 + j];
            }
        }
        scp[tab][g][m] = s;
    }
    __syncthreads();
    // softmax per table: wave 0 -> tabA, wave 1 -> tabB
    if (t < 128) {
        int tab = t >> 6, m = t & 63;
        float v = (m < MM) ? (scp[tab][0][m] + scp[tab][1][m] + attn_b[0]) : -1e30f;
        float mx = v;
        #pragma unroll
        for (int o = 32; o > 0; o >>= 1) mx = fmaxf(mx, __shfl_xor(mx, o, 64));
        float ev = (m < MM) ? __expf(v - mx) : 0.f;
        float sm = ev;
        #pragma unroll
        for (int o = 32; o > 0; o >>= 1) sm += __shfl_xor(sm, o, 64);
        if (m < MM) scw[tab * 64 + m] = ev / sm;
    }
    __syncthreads();
    // agg: tab = t>>7, d = t&127
    int tab = t >> 7, d = t & 127;
    float agg = 0.f;
    #pragma unroll 5
    for (int m = 0; m < MM; ++m)
        agg += scw[tab * 64 + m] * bf2f(proj[(tab * MM + m) * 136 + d]);
    // gate scalar per table (2 waves each)
    float gpart = agg * gw[d];
    #pragma unroll
    for (int o = 32; o > 0; o >>= 1) gpart += __shfl_xor(gpart, o, 64);
    if ((t & 63) == 0) redg[t >> 6] = gpart;
    __syncthreads();
    if (t == 0)  gateS[0] = sigf(redg[0] + redg[1] + gate_lb[0] + gate_b[0]);
    if (t == 64) gateS[1] = sigf(redg[2] + redg[3] + gate_lb[0] + gate_b[0]);
    __syncthreads();
    float embd = emb[(size_t)selfid * D + d];
    float val = gateS[tab] * agg + (1.f - gateS[tab]) * embd;
    if (tab == 1) oth[d] = val;
    __syncthreads();
    if (tab == 0) {
        float r = 0.5f * (val + oth[d]);
        outp[d] = r;
        if (isq) qvbf[(size_t)item * DM + side * D + d] = f2bf(r);
    }
}

// ---------------------------------------------------------------------------
// Kernel 3 (split): support vector -> sg.
// ---------------------------------------------------------------------------
__global__ __launch_bounds__(256) void k_sg1(
    const float* __restrict__ sv, const float* __restrict__ p1_W,
    const float* __restrict__ p1_b, float* __restrict__ hid)
{
    __shared__ float s[DM];
    int t = threadIdx.x;
    s[t] = sv[t];
    __syncthreads();
    int j = blockIdx.x * 32 + (t >> 3);   // 16 blocks * 32 rows = 512
    int pp = t & 7;                       // 8 lanes per row, 32 cols each
    const float* w = p1_W + (size_t)j * DM + pp * 32;
    float a = 0.f;
    #pragma unroll
    for (int i = 0; i < 8; ++i) {
        float4 v = *(const float4*)(w + i * 4);
        int c = pp * 32 + i * 4;
        a += v.x * s[c] + v.y * s[c + 1] + v.z * s[c + 2] + v.w * s[c + 3];
    }
    a += __shfl_xor(a, 1, 64);
    a += __shfl_xor(a, 2, 64);
    a += __shfl_xor(a, 4, 64);
    if (pp == 0) hid[j] = fmaxf(a + p1_b[j], 0.f);
}

__global__ __launch_bounds__(256) void k_sg2(
    const float* __restrict__ sv, const float* __restrict__ hid,
    const float* __restrict__ p2_W, const float* __restrict__ p2_b,
    float* __restrict__ h)
{
    __shared__ float hs[2 * DM];
    int t = threadIdx.x;
    hs[t] = hid[t]; hs[t + 256] = hid[t + 256];
    __syncthreads();
    int r = blockIdx.x * 32 + (t >> 3);   // 8 blocks * 32 rows = 256
    int pp = t & 7;                       // 8 lanes per row, 64 cols each
    const float* w = p2_W + (size_t)r * (2 * DM) + pp * 64;
    float a = 0.f;
    #pragma unroll
    for (int i = 0; i < 16; ++i) {
        float4 v = *(const float4*)(w + i * 4);
        int c = pp * 64 + i * 4;
        a += v.x * hs[c] + v.y * hs[c + 1] + v.z * hs[c + 2] + v.w * hs[c + 3];
    }
    a += __shfl_xor(a, 1, 64);
    a += __shfl_xor(a, 2, 64);
    a += __shfl_xor(a, 4, 64);
    if (pp == 0) h[r] = a + p2_b[r] + sv[r];
}

__global__ __launch_bounds__(256) void k_sg3(
    const float* __restrict__ h, const float* __restrict__ ln_a,
    const float* __restrict__ ln_b, float* __restrict__ sg)
{
    __shared__ float red[8];
    int t = threadIdx.x;
    float x = h[t];
    float sm = x;
    #pragma unroll
    for (int o = 32; o > 0; o >>= 1) sm += __shfl_xor(sm, o, 64);
    if ((t & 63) == 0) red[t >> 6] = sm;
    __syncthreads();
    float mu = (red[0] + red[1] + red[2] + red[3]) * (1.0f / 256.0f);
    float dv = x - mu;
    float sq = dv * dv;
    #pragma unroll
    for (int o = 32; o > 0; o >>= 1) sq += __shfl_xor(sq, o, 64);
    if ((t & 63) == 0) red[4 + (t >> 6)] = sq;
    __syncthreads();
    float var = (red[4] + red[5] + red[6] + red[7]) * (1.0f / 255.0f);  // ddof=1
    float sig = sqrtf(var);
    sg[t] = dv / (sig + 0.001f) * ln_a[t] + ln_b[t];
}

// ---------------------------------------------------------------------------
// Kernel 4: sgW[k] = sum_j sg[j] * Whh[k, 256+j]  (constant over batch).
// ---------------------------------------------------------------------------
__global__ __launch_bounds__(256) void k_sgwhh(
    const float* __restrict__ sg, const float* __restrict__ Whh,
    float* __restrict__ sgW)
{
    __shared__ float s[DM];
    int t = threadIdx.x;
    s[t] = sg[t];
    __syncthreads();
    int k = blockIdx.x * 64 + (t >> 2);   // 32 blocks * 64 rows = 2048
    int pp = t & 3;                       // 4 lanes per row, 64 cols each
    const float* w = Whh + (size_t)k * HSZ + DM + pp * 64;
    float a = 0.f;
    #pragma unroll
    for (int i = 0; i < 16; ++i) {
        float4 v = *(const float4*)(w + i * 4);
        int c = pp * 64 + i * 4;
        a += v.x * s[c] + v.y * s[c + 1] + v.z * s[c + 2] + v.w * s[c + 3];
    }
    a += __shfl_xor(a, 1, 64);
    a += __shfl_xor(a, 2, 64);
    if (pp == 0) sgW[k] = a;
}

// ---------------------------------------------------------------------------
// Kernel 5: FULLY FUSED 4-step LSTM, dead-half trimmed (verified R6:
// absmax unchanged, -42us vs 4-launch path).  Block = 16 batch rows, 512
// threads (8 waves), grid 256.  Wave w owns H-col tiles {w, w+8} for ALL
// FOUR gates -> c-update fully in-wave.  hq passes between steps via an
// 8.4 KB LDS bf16 A-buffer.  g0 bf16-packed, c fp32, no global state traffic.
// ---------------------------------------------------------------------------
__global__ __launch_bounds__(512, 2) void k_lstm_fused(
    const float* __restrict__ qv, const unsigned short* __restrict__ qvbf,
    const unsigned short* __restrict__ Wihp, const unsigned short* __restrict__ Whhp,
    const float* __restrict__ gb, const float* __restrict__ sgW,
    const float* __restrict__ sg, float* __restrict__ out)
{
    __shared__ unsigned short Ab[16 * 264];    // 8448 B, hq tile between steps
    __shared__ float redbuf[8][16];
    int t = threadIdx.x;
    int lane = t & 63, w = t >> 6;
    int nl = lane & 15, quad = lane >> 4;
    int b0 = blockIdx.x * 16;

    // fill A with qvbf rows (step-1 input); 512 threads x 1 int4 = 16x256
    {
        int row = t >> 5, c16 = t & 31;
        *(int4*)(Ab + row * 264 + c16 * 8) =
            *(const int4*)(qvbf + (size_t)(b0 + row) * DM + c16 * 8);
    }
    int kt[2] = { w, w + 8 };              // this wave's H-col tiles (<16)

    float sgWreg[2][4], qvreg[2][4], sgreg2[2];
    float cc[2][4];                        // c state, fp32
    ushort4 g0s[2][4];                     // g0 state, bf16 packed
    #pragma unroll
    for (int j = 0; j < 2; ++j) {
        #pragma unroll
        for (int g = 0; g < 4; ++g)
            sgWreg[j][g] = sgW[g * 512 + kt[j] * 16 + nl];
        sgreg2[j] = sg[kt[j] * 16 + nl];
        #pragma unroll
        for (int r = 0; r < 4; ++r)
            qvreg[j][r] = qv[(size_t)(b0 + quad * 4 + r) * DM + kt[j] * 16 + nl];
    }
    __syncthreads();

    // ---- steps 1..3 (write hq back to Ab) ----
    #pragma unroll 1
    for (int st = 0; st < 3; ++st) {
        short8 af[8];
        #pragma unroll
        for (int ks = 0; ks < 8; ++ks)
            af[ks] = *(const short8*)(Ab + nl * 264 + ks * 32 + quad * 8);
        const unsigned short* Bp = (st == 0) ? Wihp : Whhp;
        floatx4 acc[2][4];
        #pragma unroll
        for (int j = 0; j < 2; ++j)
            #pragma unroll
            for (int g = 0; g < 4; ++g)
                acc[j][g] = (floatx4){0.f, 0.f, 0.f, 0.f};
        #pragma unroll
        for (int j = 0; j < 2; ++j)
            #pragma unroll
            for (int g = 0; g < 4; ++g) {
                int T = g * 32 + kt[j];
                #pragma unroll
                for (int ks = 0; ks < 8; ++ks) {
                    short8 bfr = *(const short8*)(Bp + ((size_t)(T * 8 + ks) * 64 + lane) * 8);
                    acc[j][g] = __builtin_amdgcn_mfma_f32_16x16x32_bf16(
                        af[ks], bfr, acc[j][g], 0, 0, 0);
                }
            }
        float hval[2][4];
        if (st == 0) {
            #pragma unroll
            for (int j = 0; j < 2; ++j) {
                float bi  = gb[0 * 512 + kt[j] * 16 + nl];
                float bf_ = gb[1 * 512 + kt[j] * 16 + nl];
                float bg  = gb[2 * 512 + kt[j] * 16 + nl];
                float bo  = gb[3 * 512 + kt[j] * 16 + nl];
                #pragma unroll
                for (int r = 0; r < 4; ++r) {
                    float gi_ = acc[j][0][r] + bi;
                    float gf_ = acc[j][1][r] + bf_;
                    float gg_ = acc[j][2][r] + bg;
                    float go_ = acc[j][3][r] + bo;
                    ((unsigned short*)&g0s[j][0])[r] = f2bf(gi_);
                    ((unsigned short*)&g0s[j][1])[r] = f2bf(gf_);
                    ((unsigned short*)&g0s[j][2])[r] = f2bf(gg_);
                    ((unsigned short*)&g0s[j][3])[r] = f2bf(go_);
                    float cn = sigf(gi_) * tanhfast(gg_);
                    cc[j][r] = cn;
                    hval[j][r] = qvreg[j][r] + sigf(go_) * tanhfast(cn);
                }
            }
        } else {
            #pragma unroll
            for (int j = 0; j < 2; ++j)
                #pragma unroll
                for (int r = 0; r < 4; ++r) {
                    float gi_ = acc[j][0][r] + sgWreg[j][0] + bf2f(((unsigned short*)&g0s[j][0])[r]);
                    float gf_ = acc[j][1][r] + sgWreg[j][1] + bf2f(((unsigned short*)&g0s[j][1])[r]);
                    float gg_ = acc[j][2][r] + sgWreg[j][2] + bf2f(((unsigned short*)&g0s[j][2])[r]);
                    float go_ = acc[j][3][r] + sgWreg[j][3] + bf2f(((unsigned short*)&g0s[j][3])[r]);
                    float cn = sigf(gf_) * cc[j][r] + sigf(gi_) * tanhfast(gg_);
                    cc[j][r] = cn;
                    hval[j][r] = qvreg[j][r] + sigf(go_) * tanhfast(cn);
                }
        }
        __syncthreads();   // all waves done READING Ab
        #pragma unroll
        for (int j = 0; j < 2; ++j)
            #pragma unroll
            for (int r = 0; r < 4; ++r)
                Ab[(quad * 4 + r) * 264 + kt[j] * 16 + nl] = f2bf(hval[j][r]);
        __syncthreads();   // writes visible
    }

    // ---- step 4: dot(hq4, sg) into out ----
    {
        short8 af[8];
        #pragma unroll
        for (int ks = 0; ks < 8; ++ks)
            af[ks] = *(const short8*)(Ab + nl * 264 + ks * 32 + quad * 8);
        floatx4 acc[2][4];
        #pragma unroll
        for (int j = 0; j < 2; ++j)
            #pragma unroll
            for (int g = 0; g < 4; ++g)
                acc[j][g] = (floatx4){0.f, 0.f, 0.f, 0.f};
        #pragma unroll
        for (int j = 0; j < 2; ++j)
            #pragma unroll
            for (int g = 0; g < 4; ++g) {
                int T = g * 32 + kt[j];
                #pragma unroll
                for (int ks = 0; ks < 8; ++ks) {
                    short8 bfr = *(const short8*)(Whhp + ((size_t)(T * 8 + ks) * 64 + lane) * 8);
                    acc[j][g] = __builtin_amdgcn_mfma_f32_16x16x32_bf16(
                        af[ks], bfr, acc[j][g], 0, 0, 0);
                }
            }
        float part[4] = {0.f, 0.f, 0.f, 0.f};
        #pragma unroll
        for (int j = 0; j < 2; ++j)
            #pragma unroll
            for (int r = 0; r < 4; ++r) {
                float gi_ = acc[j][0][r] + sgWreg[j][0] + bf2f(((unsigned short*)&g0s[j][0])[r]);
                float gf_ = acc[j][1][r] + sgWreg[j][1] + bf2f(((unsigned short*)&g0s[j][1])[r]);
                float gg_ = acc[j][2][r] + sgWreg[j][2] + bf2f(((unsigned short*)&g0s[j][2])[r]);
                float go_ = acc[j][3][r] + sgWreg[j][3] + bf2f(((unsigned short*)&g0s[j][3])[r]);
                float cn = sigf(gf_) * cc[j][r] + sigf(gi_) * tanhfast(gg_);
                float h = qvreg[j][r] + sigf(go_) * tanhfast(cn);
                part[r] += h * sgreg2[j];
            }
        #pragma unroll
        for (int r = 0; r < 4; ++r) {
            float p = part[r];
            p += __shfl_xor(p, 1, 64);
            p += __shfl_xor(p, 2, 64);
            p += __shfl_xor(p, 4, 64);
            p += __shfl_xor(p, 8, 64);
            if (nl == 0) redbuf[w][quad * 4 + r] = p;
        }
    }
    __syncthreads();
    if (t < 16) {
        float s = 0.f;
        #pragma unroll
        for (int w2 = 0; w2 < 8; ++w2) s += redbuf[w2][t];
        out[b0 + t] = s;
    }
}

// ---------------------------------------------------------------------------
extern "C" void kernel_launch(void* const* d_in, const int* in_sizes, int n_in,
                              void* d_out, int out_size, void* d_ws, size_t ws_size,
                              hipStream_t stream) {
    const int* query   = (const int*)d_in[0];
    const int* support = (const int*)d_in[1];
    const int* q_l1 = (const int*)d_in[2];
    const int* q_l2 = (const int*)d_in[3];
    const int* q_r1 = (const int*)d_in[5];
    const int* q_r2 = (const int*)d_in[6];
    const int* s_l1 = (const int*)d_in[8];
    const int* s_l2 = (const int*)d_in[9];
    const int* s_r1 = (const int*)d_in[11];
    const int* s_r2 = (const int*)d_in[12];
    const float* emb    = (const float*)d_in[14];
    const float* gcn_W  = (const float*)d_in[15];
    const float* gcn_lb = (const float*)d_in[16];
    const float* gcn_b  = (const float*)d_in[17];
    const float* attn_W = (const float*)d_in[18];
    const float* attn_b = (const float*)d_in[19];
    const float* gate_W = (const float*)d_in[20];
    const float* gate_lb = (const float*)d_in[21];
    const float* gate_b  = (const float*)d_in[22];
    const float* p1_W = (const float*)d_in[23];
    const float* p1_b = (const float*)d_in[24];
    const float* p2_W = (const float*)d_in[25];
    const float* p2_b = (const float*)d_in[26];
    const float* ln_a = (const float*)d_in[27];
    const float* ln_b = (const float*)d_in[28];
    const float* Wih  = (const float*)d_in[29];
    const float* Whh  = (const float*)d_in[30];
    const float* bih  = (const float*)d_in[31];
    const float* bhh  = (const float*)d_in[32];

    // workspace layout: bf16 buffers first, then fp32 (16B-aligned blocks)
    unsigned short* P1   = (unsigned short*)d_ws;               // (V+1)*128
    unsigned short* P2   = P1 + (size_t)(VSZ + 1) * D;
    unsigned short* Wb   = P2 + (size_t)(VSZ + 1) * D;          // 256*128
    unsigned short* Wihp = Wb + 256 * 128;                      // 65536*8
    unsigned short* Whhp = Wihp + (size_t)65536 * 8;            // 65536*8
    unsigned short* qvbf = Whhp + (size_t)65536 * 8;            // NB*256
    float* fws = (float*)(qvbf + (size_t)NB * DM);
    float* gbv = fws;  fws += G4;
    float* qvb = fws;  fws += (size_t)NB * DM;                  // 4 MB
    float* svb = fws;  fws += DM;
    float* sgb = fws;  fws += DM;
    float* sgW = fws;  fws += G4 + 4;   // keep next block 16B-aligned
    float* hidb = fws; fws += 2 * DM;   // 512
    float* hb  = fws;  fws += DM;       // 256
    (void)in_sizes; (void)n_in; (void)out_size; (void)ws_size;

    k_pack<<<648, 256, 0, stream>>>(
        Wih, Whh, bih, bhh, gcn_W, Wihp, Whhp, gbv, Wb);
    k_proj_mfma<<<768, 256, 0, stream>>>(
        emb, Wb, gcn_lb, gcn_b, P1, P2, VSZ + 1);
    k_nbr<<<2 * (NB + 1), 256, 0, stream>>>(
        query, support, q_l1, q_l2, q_r1, q_r2, s_l1, s_l2, s_r1, s_r2,
        P1, P2, emb, attn_W, attn_b, gate_W, gate_lb, gate_b, qvb, qvbf, svb);
    k_sg1<<<16, 256, 0, stream>>>(svb, p1_W, p1_b, hidb);
    k_sg2<<<8, 256, 0, stream>>>(svb, hidb, p2_W, p2_b, hb);
    k_sg3<<<1, 256, 0, stream>>>(hb, ln_a, ln_b, sgb);
    k_sgwhh<<<32, 256, 0, stream>>>(sgb, Whh, sgW);
    k_lstm_fused<<<256, 512, 0, stream>>>(
        qvb, qvbf, Wihp, Whhp, gbv, sgW, sgb, (float*)d_out);
}